// Round 1
// baseline (342.604 us; speedup 1.0000x reference)
//
#include <hip/hip_runtime.h>

#define NN 16

// quad_perm broadcast: every lane in a quad (4 contiguous lanes) receives the
// value held by quad-lane CTRL/0x55 (CTRL in {0x00,0x55,0xAA,0xFF}).
template<int CTRL>
__device__ __forceinline__ float qb(float v) {
  return __int_as_float(__builtin_amdgcn_update_dpp(
      0, __float_as_int(v), CTRL, 0xF, 0xF, true));
}

#define ACC4(K, BV)                  \
  n0 = fmaf((BV), ac[K][0], n0);     \
  n1 = fmaf((BV), ac[K][1], n1);     \
  n2 = fmaf((BV), ac[K][2], n2);     \
  n3 = fmaf((BV), ac[K][3], n3);

// One quad-step of Trow' = Trow @ X : broadcast T[r][4Q+j] from quad-lane Q,
// multiply into register-cached X columns.
#define QSTEP_A(Q, CTRL)                                                   \
  {                                                                        \
    float b0 = qb<CTRL>(t0), b1 = qb<CTRL>(t1), b2 = qb<CTRL>(t2),         \
          b3 = qb<CTRL>(t3);                                               \
    ACC4(4 * Q + 0, b0)                                                    \
    ACC4(4 * Q + 1, b1)                                                    \
    ACC4(4 * Q + 2, b2)                                                    \
    ACC4(4 * Q + 3, b3)                                                    \
  }

// One quad-step of Unew = E @ U : broadcast E[r][4Q+j], U rows from LDS.
#define QSTEP_U(Q, CTRL)                                                   \
  {                                                                        \
    float b0 = qb<CTRL>(e0), b1 = qb<CTRL>(e1), b2 = qb<CTRL>(e2),         \
          b3 = qb<CTRL>(e3);                                               \
    float4 u0 = *(const float4*)&Ub[4 * Q + 0][4 * q];                     \
    float4 u1 = *(const float4*)&Ub[4 * Q + 1][4 * q];                     \
    float4 u2 = *(const float4*)&Ub[4 * Q + 2][4 * q];                     \
    float4 u3 = *(const float4*)&Ub[4 * Q + 3][4 * q];                     \
    n0 = fmaf(b0, u0.x, n0); n1 = fmaf(b0, u0.y, n1);                      \
    n2 = fmaf(b0, u0.z, n2); n3 = fmaf(b0, u0.w, n3);                      \
    n0 = fmaf(b1, u1.x, n0); n1 = fmaf(b1, u1.y, n1);                      \
    n2 = fmaf(b1, u1.z, n2); n3 = fmaf(b1, u1.w, n3);                      \
    n0 = fmaf(b2, u2.x, n0); n1 = fmaf(b2, u2.y, n1);                      \
    n2 = fmaf(b2, u2.z, n2); n3 = fmaf(b2, u2.w, n3);                      \
    n0 = fmaf(b3, u3.x, n0); n1 = fmaf(b3, u3.y, n1);                      \
    n2 = fmaf(b3, u3.z, n2); n3 = fmaf(b3, u3.w, n3);                      \
  }

// expm(-X) for one 16x16 fp32 matrix, computed cooperatively by one wave.
// Lane (r = l>>2, q = l&3) returns e[0..3] = expm(-X)[r][4q..4q+3].
// Taylor to order 10: E = I - X + X^2/2 - ... (||X||2 <~ 1.1 -> err < 2e-7).
__device__ __forceinline__ void expm_neg(const float* __restrict__ A, int r,
                                         int q, float e[4]) {
  // Register-cache this lane's 4 columns of X: ac[k][m] = X[k][4q+m].
  float ac[NN][4];
#pragma unroll
  for (int k = 0; k < NN; ++k) {
    float4 v = *(const float4*)(A + k * NN + 4 * q);
    ac[k][0] = v.x; ac[k][1] = v.y; ac[k][2] = v.z; ac[k][3] = v.w;
  }
  // Current power row chunk: T1 = X, T[r][4q..4q+3].
  float4 tv = *(const float4*)(A + r * NN + 4 * q);
  float t0 = tv.x, t1 = tv.y, t2 = tv.z, t3 = tv.w;
  // E = I - X
  e[0] = ((4 * q + 0) == r ? 1.f : 0.f) - t0;
  e[1] = ((4 * q + 1) == r ? 1.f : 0.f) - t1;
  e[2] = ((4 * q + 2) == r ? 1.f : 0.f) - t2;
  e[3] = ((4 * q + 3) == r ? 1.f : 0.f) - t3;
  constexpr float SK[11] = {0.f,          0.f,           1.f / 2.f,
                            -1.f / 6.f,   1.f / 24.f,    -1.f / 120.f,
                            1.f / 720.f,  -1.f / 5040.f, 1.f / 40320.f,
                            -1.f / 362880.f, 1.f / 3628800.f};
#pragma unroll
  for (int kk = 2; kk <= 10; ++kk) {
    float n0 = 0.f, n1 = 0.f, n2 = 0.f, n3 = 0.f;
    QSTEP_A(0, 0x00)
    QSTEP_A(1, 0x55)
    QSTEP_A(2, 0xAA)
    QSTEP_A(3, 0xFF)
    e[0] = fmaf(SK[kk], n0, e[0]);
    e[1] = fmaf(SK[kk], n1, e[1]);
    e[2] = fmaf(SK[kk], n2, e[2]);
    e[3] = fmaf(SK[kk], n3, e[3]);
    t0 = n0; t1 = n1; t2 = n2; t3 = n3;
  }
}

// One wave per (batch i, segment s) chain: U = E15 @ E14 @ ... @ E0,
// Ej = expm(-x[127-i, 16 s + j]).
__global__ __launch_bounds__(64, 4) void unitary_kernel(
    const float* __restrict__ x, float* __restrict__ out) {
  __shared__ float U[2][NN][NN];  // 2 KB double buffer for the running product
  const int b = blockIdx.x;   // 0..8191
  const int i = b >> 6;       // batch index of the OUTPUT
  const int s = b & 63;       // segment
  const int l = threadIdx.x;  // 0..63
  const int r = l >> 2;       // row 0..15
  const int q = l & 3;        // column quad 0..3

  // input batch is reversed: m[::-1]
  const float* xb = x + ((size_t)(127 - i) * 1024 + (size_t)s * 16) * 256;

  // j = 0: U = E0 (product with identity)
  float uo0, uo1, uo2, uo3;
  {
    float e[4];
    expm_neg(xb, r, q, e);
    uo0 = e[0]; uo1 = e[1]; uo2 = e[2]; uo3 = e[3];
  }
  int cur = 0;
  for (int j = 1; j < 16; ++j) {
    // publish current U chunk to LDS (row-major, fully spread b128 write)
    *(float4*)&U[cur][r][4 * q] = make_float4(uo0, uo1, uo2, uo3);
    // compute Ej entirely in registers (overlaps with LDS write latency)
    float ee[4];
    expm_neg(xb + (size_t)j * 256, r, q, ee);
    float e0 = ee[0], e1 = ee[1], e2 = ee[2], e3 = ee[3];
    __syncthreads();  // single-wave block: ~free, orders write->read
    const float(*Ub)[NN] = U[cur];
    float n0 = 0.f, n1 = 0.f, n2 = 0.f, n3 = 0.f;
    QSTEP_U(0, 0x00)
    QSTEP_U(1, 0x55)
    QSTEP_U(2, 0xAA)
    QSTEP_U(3, 0xFF)
    uo0 = n0; uo1 = n1; uo2 = n2; uo3 = n3;
    cur ^= 1;
  }
  // store final chunk: lane l writes 16B at out + b*1KB + l*16B (coalesced)
  *(float4*)(out + (size_t)b * 256 + r * 16 + 4 * q) =
      make_float4(uo0, uo1, uo2, uo3);
}

extern "C" void kernel_launch(void* const* d_in, const int* in_sizes, int n_in,
                              void* d_out, int out_size, void* d_ws,
                              size_t ws_size, hipStream_t stream) {
  const float* x = (const float*)d_in[0];
  float* out = (float*)d_out;
  // 128 batches * 64 segments = 8192 chains, one 64-thread (1-wave) block each
  unitary_kernel<<<dim3(8192), dim3(64), 0, stream>>>(x, out);
}

// Round 2
// 191.280 us; speedup vs baseline: 1.7911x; 1.7911x over previous
//
#include <hip/hip_runtime.h>

typedef float f32x4 __attribute__((ext_vector_type(4)));
typedef short s16x8 __attribute__((ext_vector_type(8)));
typedef unsigned int uint;
typedef uint u32x4 __attribute__((ext_vector_type(4)));

union Frag {
  u32x4 u;
  s16x8 s;
};

// pack two fp32 -> one dword of two bf16 (round-to-nearest-ish via +0x8000,
// then v_perm_b32 grabs the high 16 bits of each). 3 VALU total.
__device__ __forceinline__ uint pack_bf16(float f0, float f1) {
  uint a = __float_as_uint(f0) + 0x8000u;
  uint b = __float_as_uint(f1) + 0x8000u;
  // result bytes [a2,a3,b2,b3] = (bf16(f1)<<16) | bf16(f0)
  return __builtin_amdgcn_perm(b, a, 0x07060302u);
}

#define LGKM0() __asm__ __volatile__("s_waitcnt lgkmcnt(0)" ::: "memory")

// expm(-A) for one 16x16 fp32 matrix via Horner Taylor (order 7), one wave.
// Returns E in MFMA C/D layout: lane (lo=l&15, g=l>>4) holds rows 4g+i, col lo.
// A is only ever used as the MFMA A operand (row-major vector loads).
//   T1 = X @ (c7 I) + c6 I ;  T <- X @ T + ck I  for ck = c5..c0, X = -(-x)…
// Here A = x and we want expm(-x): c_k = (-1)^k / k! absorbed by feeding
// X = x and using alternating-sign coefficients below with X@T products of +x.
__device__ __forceinline__ f32x4 expm_neg(const float* __restrict__ A,
                                          uint* __restrict__ bf, int lo, int g,
                                          int gl, bool low, f32x4 idm,
                                          Frag c7I) {
  // A-frag of x: lane holds x[lo][8g+j], j=0..7 (lanes g>=2 zeroed => K 16..31 dead)
  f32x4 r0 = *(const f32x4*)(A + lo * 16 + 8 * gl);
  f32x4 r1 = *(const f32x4*)(A + lo * 16 + 8 * gl + 4);
  Frag xa;
  xa.u[0] = low ? pack_bf16(r0[0], r0[1]) : 0u;
  xa.u[1] = low ? pack_bf16(r0[2], r0[3]) : 0u;
  xa.u[2] = low ? pack_bf16(r1[0], r1[1]) : 0u;
  xa.u[3] = low ? pack_bf16(r1[2], r1[3]) : 0u;

  // T1 = x @ (c7 I) + c6 I   (c_k = (-1)^k / k! for expm(-x))
  f32x4 acc = idm * (1.f / 720.f);  // c6
  f32x4 t = __builtin_amdgcn_mfma_f32_16x16x32_bf16(xa.s, c7I.s, acc, 0, 0, 0);

  const float SK[6] = {-1.f / 120.f, 1.f / 24.f, -1.f / 6.f, 0.5f, -1.f, 1.f};
#pragma unroll
  for (int kk = 0; kk < 6; ++kk) {
    // C/D -> B-frag roundtrip: lane writes its rows (4g,4g+1),(4g+2,4g+3) of
    // col lo as two packed-bf16 dwords; Bf[c*8+t] = k-pair (2t,2t+1) of col c.
    bf[lo * 8 + 2 * g] = pack_bf16(t[0], t[1]);
    bf[lo * 8 + 2 * g + 1] = pack_bf16(t[2], t[3]);
    LGKM0();
    Frag tb;
    tb.u = *(const u32x4*)&bf[lo * 8 + 4 * gl];  // k = 8g.. pairs (b128)
    acc = idm * SK[kk];
    t = __builtin_amdgcn_mfma_f32_16x16x32_bf16(xa.s, tb.s, acc, 0, 0, 0);
  }
  return t;  // = expm(-x) in C/D layout, fp32
}

// One wave per chain: U = E15 @ E14 @ ... @ E0, Ej = expm(-x[127-i, 16s+j]).
__global__ __launch_bounds__(256, 8) void unitary_kernel(
    const float* __restrict__ x, float* __restrict__ out) {
  __shared__ uint BfS[4][128];   // per-wave bf16 B-frag staging (512 B)
  __shared__ float EfS[4][256];  // per-wave fp32 row-major staging (1 KB)

  const int tid = threadIdx.x;
  const int w = tid >> 6;
  const int l = tid & 63;
  const int lo = l & 15;  // col (B/C/D) == row (A)
  const int g = l >> 4;
  const int gl = g & 1;
  const bool low = (g < 2);

  uint* bf = BfS[w];
  float* ef = EfS[w];

  const int ch = blockIdx.x * 4 + w;  // chain 0..8191
  const int bi = ch >> 6;
  const int s = ch & 63;
  const float* xb = x + ((size_t)(127 - bi) * 1024 + (size_t)s * 16) * 256;

  // identity diag mask in C/D layout (lane rows 4g+i, col lo)
  f32x4 idm;
  idm[0] = (4 * g + 0 == lo) ? 1.f : 0.f;
  idm[1] = (4 * g + 1 == lo) ? 1.f : 0.f;
  idm[2] = (4 * g + 2 == lo) ? 1.f : 0.f;
  idm[3] = (4 * g + 3 == lo) ? 1.f : 0.f;

  // B-fragment of c7 * I  (c7 = -1/5040): one bf16 at k==lo slot, lanes g<2
  Frag c7I;
  {
    uint c7b = pack_bf16(-1.f / 5040.f, 0.f) & 0xFFFFu;
    int jd = lo - 8 * gl;
    uint val = c7b << (16 * (jd & 1));
    c7I.u[0] = (low && jd >= 0 && (jd >> 1) == 0) ? val : 0u;
    c7I.u[1] = (low && jd >= 0 && (jd >> 1) == 1) ? val : 0u;
    c7I.u[2] = (low && jd >= 0 && (jd >> 1) == 2) ? val : 0u;
    c7I.u[3] = (low && jd >= 0 && (jd >> 1) == 3) ? val : 0u;
  }

  // j = 0: U = E0
  f32x4 uc = expm_neg(xb, bf, lo, g, gl, low, idm, c7I);

  for (int j = 1; j < 16; ++j) {
    f32x4 e = expm_neg(xb + (size_t)j * 256, bf, lo, g, gl, low, idm, c7I);
    // chain step: U <- E @ U  (E -> A-frag via fp32 LDS, U -> B-frag via bf16)
    ef[(4 * g + 0) * 16 + lo] = e[0];
    ef[(4 * g + 1) * 16 + lo] = e[1];
    ef[(4 * g + 2) * 16 + lo] = e[2];
    ef[(4 * g + 3) * 16 + lo] = e[3];
    bf[lo * 8 + 2 * g] = pack_bf16(uc[0], uc[1]);
    bf[lo * 8 + 2 * g + 1] = pack_bf16(uc[2], uc[3]);
    LGKM0();
    f32x4 q0 = *(const f32x4*)&ef[lo * 16 + 8 * gl];
    f32x4 q1 = *(const f32x4*)&ef[lo * 16 + 8 * gl + 4];
    Frag ea;
    ea.u[0] = low ? pack_bf16(q0[0], q0[1]) : 0u;
    ea.u[1] = low ? pack_bf16(q0[2], q0[3]) : 0u;
    ea.u[2] = low ? pack_bf16(q1[0], q1[1]) : 0u;
    ea.u[3] = low ? pack_bf16(q1[2], q1[3]) : 0u;
    Frag ub;
    ub.u = *(const u32x4*)&bf[lo * 8 + 4 * gl];
    f32x4 z = {0.f, 0.f, 0.f, 0.f};
    uc = __builtin_amdgcn_mfma_f32_16x16x32_bf16(ea.s, ub.s, z, 0, 0, 0);
  }

  // store U (C/D layout -> row-major), 4x coalesced-segment scalar stores
  float* op = out + (size_t)ch * 256;
  op[(4 * g + 0) * 16 + lo] = uc[0];
  op[(4 * g + 1) * 16 + lo] = uc[1];
  op[(4 * g + 2) * 16 + lo] = uc[2];
  op[(4 * g + 3) * 16 + lo] = uc[3];
}

extern "C" void kernel_launch(void* const* d_in, const int* in_sizes, int n_in,
                              void* d_out, int out_size, void* d_ws,
                              size_t ws_size, hipStream_t stream) {
  const float* x = (const float*)d_in[0];
  float* out = (float*)d_out;
  // 8192 chains, 4 waves (chains) per 256-thread block
  unitary_kernel<<<dim3(2048), dim3(256), 0, stream>>>(x, out);
}

// Round 3
// 190.617 us; speedup vs baseline: 1.7973x; 1.0035x over previous
//
#include <hip/hip_runtime.h>

typedef float f32x4 __attribute__((ext_vector_type(4)));
typedef short s16x8 __attribute__((ext_vector_type(8)));
typedef unsigned int uint;
typedef uint u32x4 __attribute__((ext_vector_type(4)));

union Frag {
  u32x4 u;
  s16x8 s;
};

// pack two fp32 -> dword of two bf16 (round-half-up via +0x8000)
__device__ __forceinline__ uint packhi(float f0, float f1) {
  uint a = __float_as_uint(f0) + 0x8000u;
  uint b = __float_as_uint(f1) + 0x8000u;
  return __builtin_amdgcn_perm(b, a, 0x07060302u);  // [a.hi16, b.hi16]
}

// split f into bf16 hi + bf16 residual lo; returns packed dwords for a pair
__device__ __forceinline__ void split2(float f0, float f1, uint& hi, uint& lo) {
  uint a0 = __float_as_uint(f0) + 0x8000u;
  uint a1 = __float_as_uint(f1) + 0x8000u;
  hi = __builtin_amdgcn_perm(a1, a0, 0x07060302u);
  float h0 = __uint_as_float(a0 & 0xFFFF0000u);
  float h1 = __uint_as_float(a1 & 0xFFFF0000u);
  lo = packhi(f0 - h0, f1 - h1);
}

// compiler-only memory fence: orders DS write before DS read in the emitted
// stream; HW executes same-wave DS ops in order, no s_waitcnt needed between.
#define CFENCE() __asm__ __volatile__("" ::: "memory")

// E^T = expm(-X)^T in C/D layout, via Horner Taylor order 6 on X^T.
// A operand = [Xh^T | Xl^T] split along K (exact X), B = [Th;Th] duplicated.
// hb: 192-dword per-wave scratch (stride 12/row, bank-spread, b128-aligned).
__device__ __forceinline__ f32x4 expm_negT(const float* __restrict__ A,
                                           uint* __restrict__ hb, int lo,
                                           int g, int gt, bool low, f32x4 idm) {
  // lane (lo,g) holds A-frag element X^T[lo][8gt+j] = X[8gt+j][lo]
  float c0 = A[(8 * gt + 0) * 16 + lo], c1 = A[(8 * gt + 1) * 16 + lo];
  float c2 = A[(8 * gt + 2) * 16 + lo], c3 = A[(8 * gt + 3) * 16 + lo];
  float c4 = A[(8 * gt + 4) * 16 + lo], c5 = A[(8 * gt + 5) * 16 + lo];
  float c6 = A[(8 * gt + 6) * 16 + lo], c7 = A[(8 * gt + 7) * 16 + lo];
  // X^T in C/D for the affine init: X^T[4g+i][lo] = X[lo][4g+i]
  f32x4 xr = *(const f32x4*)(A + lo * 16 + 4 * g);
  uint h, lw;
  Frag xa;
  split2(c0, c1, h, lw); xa.u[0] = low ? h : lw;
  split2(c2, c3, h, lw); xa.u[1] = low ? h : lw;
  split2(c4, c5, h, lw); xa.u[2] = low ? h : lw;
  split2(c6, c7, h, lw); xa.u[3] = low ? h : lw;
  // T = c6*X^T + c5*I  (c_k = (-1)^k/k!)
  f32x4 t;
#pragma unroll
  for (int i = 0; i < 4; ++i)
    t[i] = fmaf(1.f / 720.f, xr[i], (-1.f / 120.f) * idm[i]);
  const float SK[5] = {1.f / 24.f, -1.f / 6.f, 0.5f, -1.f, 1.f};
  uint* wp = hb + lo * 12 + 2 * g;
  const uint* rp = hb + lo * 12 + 4 * gt;
#pragma unroll
  for (int k = 0; k < 5; ++k) {
    wp[0] = packhi(t[0], t[1]);  // rows (4g,4g+1),(4g+2,4g+3) of col lo
    wp[1] = packhi(t[2], t[3]);
    CFENCE();
    Frag tb;
    tb.u = *(const u32x4*)rp;  // k-pairs 8gt..8gt+7 of col lo (halves dup)
    CFENCE();
    f32x4 acc = idm * SK[k];
    t = __builtin_amdgcn_mfma_f32_16x16x32_bf16(xa.s, tb.s, acc, 0, 0, 0);
  }
  return t;  // C/D(expm(-X)^T)
}

__global__ __launch_bounds__(256, 8) void unitary_kernel(
    const float* __restrict__ x, float* __restrict__ out) {
  __shared__ uint HB[4][192];  // Horner T staging (hi only)
  __shared__ uint PE[4][320];  // chain E staging: {h0,h1,l0,l1} stride 20
  __shared__ uint PU[4][320];  // chain U staging: {h0,h1,l0,l1} stride 20

  const int tid = threadIdx.x;
  const int w = tid >> 6;
  const int l = tid & 63;
  const int lo = l & 15;
  const int g = l >> 4;
  const int gt = g & 1;
  const bool low = g < 2;

  uint* hb = HB[w];
  uint* pe = PE[w];
  uint* pu = PU[w];

  const int ch = blockIdx.x * 4 + w;  // chain 0..8191
  const float* xb =
      x + ((size_t)(127 - (ch >> 6)) * 1024 + (size_t)(ch & 63) * 16) * 256;

  f32x4 idm;
  idm[0] = (4 * g + 0 == lo) ? 1.f : 0.f;
  idm[1] = (4 * g + 1 == lo) ? 1.f : 0.f;
  idm[2] = (4 * g + 2 == lo) ? 1.f : 0.f;
  idm[3] = (4 * g + 3 == lo) ? 1.f : 0.f;

  // B-frag of identity, halves duplicated ([I;I]) — pairs with split-A
  Frag ifr;
  {
    uint v = ((lo >> 3) == gt) ? (0x3F80u << (16 * (lo & 1))) : 0u;
    int slot = (lo >> 1) & 3;
    ifr.u[0] = (slot == 0) ? v : 0u;
    ifr.u[1] = (slot == 1) ? v : 0u;
    ifr.u[2] = (slot == 2) ? v : 0u;
    ifr.u[3] = (slot == 3) ? v : 0u;
  }

  uint* pew = pe + lo * 20 + 4 * g;
  const uint* pea = pe + lo * 20 + 8 * gt + (low ? 0 : 2);
  uint* puw = pu + lo * 20 + 4 * g;
  const uint* pub = pu + lo * 20 + 8 * gt;

  f32x4 uc;
#pragma unroll 1
  for (int j = 0; j < 16; ++j) {
    f32x4 et = expm_negT(xb + j * 256, hb, lo, g, gt, low, idm);
    uint h0, l0, h1, l1;
    split2(et[0], et[1], h0, l0);
    split2(et[2], et[3], h1, l1);
    *(u32x4*)pew = (u32x4){h0, h1, l0, l1};
    if (j) {
      split2(uc[0], uc[1], h0, l0);
      split2(uc[2], uc[3], h1, l1);
      *(u32x4*)puw = (u32x4){h0, h1, l0, l1};
    }
    CFENCE();
    // A-frag(E) = B-frag(E^T): k-regroup, hi for g<2, lo residual for g>=2
    Frag ea;
    ea.u[0] = pea[0];
    ea.u[1] = pea[1];
    ea.u[2] = pea[4];
    ea.u[3] = pea[5];
    f32x4 z = {0.f, 0.f, 0.f, 0.f};
    if (j) {
      Frag b1, b2;  // [Uh;Uh] and [Ul;Ul]
      b1.u[0] = pub[0];
      b1.u[1] = pub[1];
      b1.u[2] = pub[4];
      b1.u[3] = pub[5];
      b2.u[0] = pub[2];
      b2.u[1] = pub[3];
      b2.u[2] = pub[6];
      b2.u[3] = pub[7];
      CFENCE();
      f32x4 t1 = __builtin_amdgcn_mfma_f32_16x16x32_bf16(ea.s, b1.s, z, 0, 0, 0);
      uc = __builtin_amdgcn_mfma_f32_16x16x32_bf16(ea.s, b2.s, t1, 0, 0, 0);
    } else {
      CFENCE();
      uc = __builtin_amdgcn_mfma_f32_16x16x32_bf16(ea.s, ifr.s, z, 0, 0, 0);
    }
  }

  // store U (C/D -> row-major), coalesced 64B segments per quarter-wave
  float* op = out + (size_t)ch * 256;
  op[(4 * g + 0) * 16 + lo] = uc[0];
  op[(4 * g + 1) * 16 + lo] = uc[1];
  op[(4 * g + 2) * 16 + lo] = uc[2];
  op[(4 * g + 3) * 16 + lo] = uc[3];
}

extern "C" void kernel_launch(void* const* d_in, const int* in_sizes, int n_in,
                              void* d_out, int out_size, void* d_ws,
                              size_t ws_size, hipStream_t stream) {
  const float* x = (const float*)d_in[0];
  float* out = (float*)d_out;
  unitary_kernel<<<dim3(2048), dim3(256), 0, stream>>>(x, out);
}